// Round 1
// baseline (452.791 us; speedup 1.0000x reference)
//
#include <hip/hip_runtime.h>

#define LN_EPS 1e-5f
#define QSCALE 0.25500526578425445f  // (1/sqrt(32)) * log2(e)

typedef __attribute__((ext_vector_type(8))) short bf16x8;
typedef __attribute__((ext_vector_type(4))) float f32x4;

#define MFMA16(A, B, C) __builtin_amdgcn_mfma_f32_16x16x32_bf16(A, B, C, 0, 0, 0)

// ---------- bf16 helpers ----------
static __device__ __forceinline__ unsigned short f2bf_rne(float f) {
    union { unsigned int i; float f; } c; c.f = f;
    unsigned int i = c.i;
    return (unsigned short)((i + 0x7fffu + ((i >> 16) & 1u)) >> 16);
}
static __device__ __forceinline__ void bfstore2(unsigned short* p, float x, float y) {
    *(unsigned int*)p = (unsigned int)f2bf_rne(x) | ((unsigned int)f2bf_rne(y) << 16);
}
static __device__ __forceinline__ unsigned pk2(float a, float b) {
    return __builtin_amdgcn_perm(__builtin_bit_cast(unsigned, b),
                                 __builtin_bit_cast(unsigned, a), 0x07060302u);
}
static __device__ __forceinline__ unsigned short tb16(float f) {
    return (unsigned short)(__builtin_bit_cast(unsigned, f) >> 16);
}

// ---------- DWT ----------
__global__ void dwt_kernel(const float4* __restrict__ in, float4* __restrict__ ll,
                           float4* __restrict__ hp, int B, int H2, int W2) {
    const int i = blockIdx.x * blockDim.x + threadIdx.x;
    const int total = B * H2 * W2 * 16;
    if (i >= total) return;
    const int c4 = i & 15;
    int t = i >> 4;
    const int w2 = t % W2; t /= W2;
    const int h2 = t % H2;
    const int b = t / H2;
    const int W = W2 * 2;
    const size_t base = (((size_t)b * (H2 * 2) + 2 * h2) * W + 2 * w2) * 16 + c4;
    const float4 x00 = in[base];
    const float4 x01 = in[base + 16];
    const float4 x10 = in[base + (size_t)W * 16];
    const float4 x11 = in[base + (size_t)W * 16 + 16];
    float4 vll, vlh, vhl, vhh;
#define DWTC(a) \
    vll.a = (x00.a + x01.a + x10.a + x11.a) * 0.5f; \
    vlh.a = (x00.a - x01.a + x10.a - x11.a) * 0.5f; \
    vhl.a = (x00.a + x01.a - x10.a - x11.a) * 0.5f; \
    vhh.a = (x00.a - x01.a - x10.a + x11.a) * 0.5f;
    DWTC(x) DWTC(y) DWTC(z) DWTC(w)
#undef DWTC
    const size_t oi = ((size_t)b * H2 + h2) * W2 + w2;
    ll[oi * 16 + c4] = vll;
    hp[oi * 48 + c4] = vlh;
    hp[oi * 48 + 16 + c4] = vhl;
    hp[oi * 48 + 32 + c4] = vhh;
}

// ---------- IDWT with fused hp_out = hp + gain*att ----------
__global__ void idwt_kernel(const float4* __restrict__ cur, const float4* __restrict__ hp,
                            const float4* __restrict__ att, float gain,
                            float4* __restrict__ out, int B, int H2, int W2) {
    const int i = blockIdx.x * blockDim.x + threadIdx.x;
    const int total = B * H2 * W2 * 16;
    if (i >= total) return;
    const int c4 = i & 15;
    int t = i >> 4;
    const int w2 = t % W2; t /= W2;
    const int h2 = t % H2;
    const int b = t / H2;
    const size_t oi = ((size_t)b * H2 + h2) * W2 + w2;
    const size_t sp = (size_t)h2 * W2 + w2;
    const size_t gstr = (size_t)B * H2 * W2;
    const float4 vll = cur[oi * 16 + c4];
    float4 vlh = hp[oi * 48 + c4];
    float4 vhl = hp[oi * 48 + 16 + c4];
    float4 vhh = hp[oi * 48 + 32 + c4];
    const float4 a0 = att[((size_t)b * H2 * W2 + sp) * 16 + c4];
    const float4 a1 = att[((size_t)b * H2 * W2 + gstr + sp) * 16 + c4];
    const float4 a2 = att[((size_t)b * H2 * W2 + 2 * gstr + sp) * 16 + c4];
#define ADDG(a) \
    vlh.a = fmaf(gain, a0.a, vlh.a); \
    vhl.a = fmaf(gain, a1.a, vhl.a); \
    vhh.a = fmaf(gain, a2.a, vhh.a);
    ADDG(x) ADDG(y) ADDG(z) ADDG(w)
#undef ADDG
    float4 x00, x01, x10, x11;
#define IDWTC(a) \
    x00.a = (vll.a + vlh.a + vhl.a + vhh.a) * 0.5f; \
    x01.a = (vll.a - vlh.a + vhl.a - vhh.a) * 0.5f; \
    x10.a = (vll.a + vlh.a - vhl.a - vhh.a) * 0.5f; \
    x11.a = (vll.a - vlh.a - vhl.a + vhh.a) * 0.5f;
    IDWTC(x) IDWTC(y) IDWTC(z) IDWTC(w)
#undef IDWTC
    const int W = W2 * 2;
    const size_t r0 = (((size_t)b * (H2 * 2) + 2 * h2) * W + 2 * w2) * 16 + c4;
    out[r0] = x00;
    out[r0 + 16] = x01;
    out[r0 + (size_t)W * 16] = x10;
    out[r0 + (size_t)W * 16 + 16] = x11;
}

// ---------- weight prep: f32 -> bf16 transposed; Wq scaled by QSCALE ----------
__global__ void prep_weights(const float* __restrict__ lwq, const float* __restrict__ lwk,
                             const float* __restrict__ lwv, const float* __restrict__ lwp,
                             const float* __restrict__ hwq, const float* __restrict__ hwk,
                             const float* __restrict__ hwv, const float* __restrict__ hwp,
                             unsigned short* __restrict__ wbuf) {
    const int i = blockIdx.x * blockDim.x + threadIdx.x;
    if (i >= 65536) return;
    const int set = i >> 15;
    const int r = i & 32767;
    const float* wq = set ? hwq : lwq;
    const float* wk = set ? hwk : lwk;
    const float* wv = set ? hwv : lwv;
    const float* wp = set ? hwp : lwp;
    float v;
    if (r < 24576) {
        const int nn = r >> 6, c = r & 63;
        const float* w = (nn < 128) ? wq : (nn < 256) ? wk : wv;
        v = w[c * 128 + (nn & 127)];
        if (nn < 128) v *= QSCALE;   // fold softmax scale*log2e into Wq
    } else {
        const int r2 = r - 24576;
        const int nn = r2 >> 7, d = r2 & 127;
        v = wp[d * 64 + nn];
    }
    wbuf[i] = f2bf_rne(v);
}

// ---------- job descriptor for the fused attention kernel ----------
struct Job {
    const float* xin;     // plain input (used when mixsrc == nullptr)
    const float* mixsrc;  // hp tensor (B,S,S,192); if set, phase A mixes groups
    const float* mixw;    // 3x3 mix matrix
    float* xout;
    const float* basep;   // residual base (nullptr = none)
    float res_scale;
    const float* ln_g; const float* ln_b;
    const float* bq; const float* bk; const float* bv; const float* bp;
    const unsigned short* wqkvT;  // bf16 [384][64], Wq pre-scaled
    const unsigned short* wpT;    // bf16 [64][128]
};

// ---------- fused axial attention (MFMA), chunked K/V for occupancy ----------
// K/V are produced and consumed in CK=32-row chunks (softmax here is max-free,
// so PV and the row-sum accumulate linearly in registers across chunks).
// LDS: S=128 -> 77,824 B (2 blocks/CU), S=64 -> 53,248 B (3 blocks/CU).
template<int S>
__global__ __launch_bounds__(512, 4)
void axial_attn(Job jA, Job jB, int nA, int axis)
{
    constexpr int BS = 512;
    constexpr int NW = 8;                 // waves per block
    constexpr int CK = 32;                // k-chunk rows
    constexpr int NCH = S / CK;           // chunks
    constexpr int CSTR = 40;              // Vc / Pb stride (shorts)
    constexpr int WPH = 2;                // waves per head
    constexpr int NSI = (S / 16) / WPH;   // q-tiles per wave

    // XOR-swizzled, power-of-2 strides: physical col = col ^ ((row&7)<<3)
    __shared__ __align__(16) unsigned short Xs[S * 64];    // X after LN
    __shared__ __align__(16) unsigned short Qs[S * 128];   // Q, then Y
    __shared__ __align__(16) unsigned short Kc[CK * 128];  // K chunk
    __shared__ __align__(16) unsigned short Vc[128 * CSTR];      // V^T chunk
    __shared__ __align__(16) unsigned short Pb[NW * 16 * CSTR];  // per-wave P

    const int tid = threadIdx.x;
    const int lane = tid & 63;
    const int w = tid >> 6;
    const int n16 = lane & 15;
    const int quad = lane >> 4;

    const bool isB = (int)blockIdx.x >= nA;
    const Job j = isB ? jB : jA;
    const int line = isB ? (int)blockIdx.x - nA : (int)blockIdx.x;
    const int lb = line / S;
    const int lr = line - lb * S;
    size_t lbase, tstr; // float units
    if (axis == 1) { lbase = ((size_t)lb * S * S + lr) * 64; tstr = (size_t)S * 64; }
    else           { lbase = ((size_t)lb * S + lr) * (size_t)S * 64; tstr = 64; }

    // ---- Phase A: (optional group-mix) + LayerNorm -> Xs (bf16, swizzled) ----
    {
        const int sub = tid & 15;
        const float4 g4 = ((const float4*)j.ln_g)[sub];
        const float4 be4 = ((const float4*)j.ln_b)[sub];
        const float4* x4 = (const float4*)j.xin;
        const float4* hp4 = (const float4*)j.mixsrc;
        const size_t lbase4 = lbase >> 2, tstr4 = tstr >> 2;
        float m0, m1, m2; int bimg;
        if (hp4) {
            const int g = lb >> 2;      // B = 4 images
            bimg = lb & 3;
            m0 = j.mixw[g * 3 + 0]; m1 = j.mixw[g * 3 + 1]; m2 = j.mixw[g * 3 + 2];
        }
        for (int t = (tid >> 4); t < S; t += BS / 16) {
            float4 v;
            if (hp4) {
                const int pos = (axis == 1) ? (t * S + lr) : (lr * S + t);
                const size_t hb = ((size_t)bimg * S * S + pos) * 48 + sub;
                const float4 h0 = hp4[hb];
                const float4 h1 = hp4[hb + 16];
                const float4 h2 = hp4[hb + 32];
                v.x = m0 * h0.x + m1 * h1.x + m2 * h2.x;
                v.y = m0 * h0.y + m1 * h1.y + m2 * h2.y;
                v.z = m0 * h0.z + m1 * h1.z + m2 * h2.z;
                v.w = m0 * h0.w + m1 * h1.w + m2 * h2.w;
            } else {
                v = x4[lbase4 + (size_t)t * tstr4 + sub];
            }
            float s = v.x + v.y + v.z + v.w;
            float ss = v.x * v.x + v.y * v.y + v.z * v.z + v.w * v.w;
            #pragma unroll
            for (int m = 1; m < 16; m <<= 1) {
                s += __shfl_xor(s, m);
                ss += __shfl_xor(ss, m);
            }
            const float mean = s * 0.015625f;
            const float rstd = rsqrtf(ss * 0.015625f - mean * mean + LN_EPS);
            unsigned short* xr = &Xs[(t << 6) + ((sub * 4) ^ ((t & 7) << 3))];
            bfstore2(xr,     (v.x - mean) * rstd * g4.x + be4.x,
                             (v.y - mean) * rstd * g4.y + be4.y);
            bfstore2(xr + 2, (v.z - mean) * rstd * g4.z + be4.z,
                             (v.w - mean) * rstd * g4.w + be4.w);
        }
    }
    __syncthreads();

    // ---- Phase B: Q = X @ Wq + bq (one 16-col tile per wave) ----
    {
        const int nt = w;                 // 8 col-tiles, 8 waves
        const int cbase = nt * 16;
        const float bias = j.bq[cbase + n16] * QSCALE;
        const bf16x8 Bf0 = *(const bf16x8*)&j.wqkvT[(nt * 16 + n16) * 64 + quad * 8];
        const bf16x8 Bf1 = *(const bf16x8*)&j.wqkvT[(nt * 16 + n16) * 64 + 32 + quad * 8];
        #pragma unroll
        for (int mt = 0; mt < S / 16; ++mt) {
            const int xr = mt * 16 + n16;
            const int xm = (xr & 7) << 3;
            const bf16x8 A0 = *(const bf16x8*)&Xs[(xr << 6) + ((quad * 8) ^ xm)];
            const bf16x8 A1 = *(const bf16x8*)&Xs[(xr << 6) + ((32 + quad * 8) ^ xm)];
            f32x4 acc = {bias, bias, bias, bias};
            acc = MFMA16(A0, Bf0, acc);
            acc = MFMA16(A1, Bf1, acc);
            const int row0 = mt * 16 + quad * 4;
            #pragma unroll
            for (int r = 0; r < 4; ++r) {
                const int rr = row0 + r;
                Qs[(rr << 7) + ((cbase + n16) ^ ((rr & 7) << 3))] = tb16(acc[r]);
            }
        }
    }
    __syncthreads();

    // ---- Phase C: chunked attention ----
    const int h = w >> 1;
    const int sub = w & 1;
    const int hoff = h * 32;
    unsigned short* pbw = &Pb[w * 16 * CSTR];
    const bf16x8 ones = (bf16x8)(short)0x3F80;

    // hoist Q fragments (Qs region will be overwritten by this wave's own Y)
    bf16x8 qb[NSI];
    #pragma unroll
    for (int si = 0; si < NSI; ++si) {
        const int qr = (sub * NSI + si) * 16 + n16;
        qb[si] = *(const bf16x8*)&Qs[(qr << 7) + ((hoff + quad * 8) ^ ((qr & 7) << 3))];
    }
    f32x4 accl[NSI], y0[NSI], y1[NSI];
    #pragma unroll
    for (int si = 0; si < NSI; ++si) {
        accl[si] = (f32x4){0.f, 0.f, 0.f, 0.f};
        y0[si]   = (f32x4){0.f, 0.f, 0.f, 0.f};
        y1[si]   = (f32x4){0.f, 0.f, 0.f, 0.f};
    }

    for (int kc = 0; kc < NCH; ++kc) {
        const int k0 = kc * CK;
        // -- produce K,V chunk (4 tiles per wave; waves 0-3: K, 4-7: V) --
        #pragma unroll
        for (int i = 0; i < 4; ++i) {
            const int tix = w * 4 + i;      // 0..31
            const int region = tix >> 4;    // 0=K, 1=V
            const int rem = tix & 15;
            const int nt = rem >> 1;
            const int mtl = rem & 1;
            const int wnt = 8 + region * 8 + nt;
            const bf16x8 W0 = *(const bf16x8*)&j.wqkvT[(wnt * 16 + n16) * 64 + quad * 8];
            const bf16x8 W1 = *(const bf16x8*)&j.wqkvT[(wnt * 16 + n16) * 64 + 32 + quad * 8];
            const float* bb = region ? j.bv : j.bk;
            const float bias = bb[nt * 16 + n16];
            const int xr = k0 + mtl * 16 + n16;
            const int xm = (xr & 7) << 3;
            const bf16x8 A0 = *(const bf16x8*)&Xs[(xr << 6) + ((quad * 8) ^ xm)];
            const bf16x8 A1 = *(const bf16x8*)&Xs[(xr << 6) + ((32 + quad * 8) ^ xm)];
            f32x4 acc = {bias, bias, bias, bias};
            acc = MFMA16(A0, W0, acc);
            acc = MFMA16(A1, W1, acc);
            if (region == 0) {
                const int row0 = mtl * 16 + quad * 4;
                #pragma unroll
                for (int r = 0; r < 4; ++r) {
                    const int rr = row0 + r;
                    Kc[(rr << 7) + ((nt * 16 + n16) ^ ((rr & 7) << 3))] = tb16(acc[r]);
                }
            } else {
                *(uint2*)&Vc[(nt * 16 + n16) * CSTR + mtl * 16 + quad * 4] =
                    make_uint2(pk2(acc[0], acc[1]), pk2(acc[2], acc[3]));
            }
        }
        __syncthreads();

        // -- consume chunk: scores + exp + PV accumulate --
        const bf16x8 vb0 = *(const bf16x8*)&Vc[(hoff + n16) * CSTR + quad * 8];
        const bf16x8 vb1 = *(const bf16x8*)&Vc[(hoff + 16 + n16) * CSTR + quad * 8];
        const int km = (n16 & 7) << 3;
        const bf16x8 ka0 = *(const bf16x8*)&Kc[(n16 << 7) + ((hoff + quad * 8) ^ km)];
        const bf16x8 ka1 = *(const bf16x8*)&Kc[((16 + n16) << 7) + ((hoff + quad * 8) ^ km)];
        #pragma unroll
        for (int si = 0; si < NSI; ++si) {
            f32x4 sc0 = {0.f, 0.f, 0.f, 0.f};
            f32x4 sc1 = {0.f, 0.f, 0.f, 0.f};
            sc0 = MFMA16(ka0, qb[si], sc0);
            sc1 = MFMA16(ka1, qb[si], sc1);
            *(uint2*)&pbw[n16 * CSTR + quad * 4] = make_uint2(
                pk2(__builtin_amdgcn_exp2f(sc0[0]), __builtin_amdgcn_exp2f(sc0[1])),
                pk2(__builtin_amdgcn_exp2f(sc0[2]), __builtin_amdgcn_exp2f(sc0[3])));
            *(uint2*)&pbw[n16 * CSTR + 16 + quad * 4] = make_uint2(
                pk2(__builtin_amdgcn_exp2f(sc1[0]), __builtin_amdgcn_exp2f(sc1[1])),
                pk2(__builtin_amdgcn_exp2f(sc1[2]), __builtin_amdgcn_exp2f(sc1[3])));
            const bf16x8 pa = *(const bf16x8*)&pbw[n16 * CSTR + quad * 8];
            accl[si] = MFMA16(pa, ones, accl[si]);
            y0[si] = MFMA16(pa, vb0, y0[si]);
            y1[si] = MFMA16(pa, vb1, y1[si]);
        }
        __syncthreads();
    }

    // ---- Y normalize -> Qs (same-wave region as the hoisted Q frags) ----
    #pragma unroll
    for (int si = 0; si < NSI; ++si) {
        const int q0 = (sub * NSI + si) * 16;
        #pragma unroll
        for (int r = 0; r < 4; ++r) {
            const float inv = __builtin_amdgcn_rcpf(accl[si][r]);
            const int row = q0 + quad * 4 + r;
            const int m = (row & 7) << 3;
            Qs[(row << 7) + ((hoff + n16) ^ m)]      = tb16(y0[si][r] * inv);
            Qs[(row << 7) + ((hoff + 16 + n16) ^ m)] = tb16(y1[si][r] * inv);
        }
    }
    __syncthreads();

    // ---- Phase D: out = Y @ Wp + bp (+ residual) ----
    {
        constexpr int TD = (S / 16) * 4 / NW;   // 4 for S=128, 2 for S=64
        const int mt = (w * TD) >> 2;           // constant per wave
        const int nt0 = (w * TD) & 3;
        const int m0 = mt * 16;
        const int ym = (n16 & 7) << 3;
        bf16x8 pa[4];
        #pragma unroll
        for (int kt = 0; kt < 4; ++kt)
            pa[kt] = *(const bf16x8*)&Qs[((m0 + n16) << 7) + ((kt * 32 + quad * 8) ^ ym)];
        #pragma unroll
        for (int i = 0; i < TD; ++i) {
            const int nt = nt0 + i;
            const float bias = j.bp[nt * 16 + n16];
            f32x4 acc = {bias, bias, bias, bias};
            #pragma unroll
            for (int kt = 0; kt < 4; ++kt) {
                const bf16x8 wb = *(const bf16x8*)&j.wpT[(nt * 16 + n16) * 128 + kt * 32 + quad * 8];
                acc = MFMA16(pa[kt], wb, acc);
            }
            #pragma unroll
            for (int r = 0; r < 4; ++r) {
                const size_t gi = lbase + (size_t)(m0 + quad * 4 + r) * tstr + nt * 16 + n16;
                float v = acc[r];
                if (j.basep) v = fmaf(j.res_scale, v, j.basep[gi]);
                j.xout[gi] = v;
            }
        }
    }
}

extern "C" void kernel_launch(void* const* d_in, const int* in_sizes, int n_in,
                              void* d_out, int out_size, void* d_ws, size_t ws_size,
                              hipStream_t stream) {
    (void)in_sizes; (void)n_in; (void)out_size; (void)ws_size;
    const float* x = (const float*)d_in[0];
    const float* P_lp[10];
    const float* P_hp[10];
    for (int i = 0; i < 10; ++i) P_lp[i] = (const float*)d_in[1 + i];
    for (int i = 0; i < 10; ++i) P_hp[i] = (const float*)d_in[11 + i];
    const float* mw0 = (const float*)d_in[21];
    const float* mw1 = (const float*)d_in[22];
    float* out = (float*)d_out;
    float* ws = (float*)d_ws;

    // ---- workspace map (floats) ----
    float* ll0 = ws;                         // [0,4.19M)     cur0; read by final idwt
    float* hp0 = ll0 + (size_t)4194304;      // [4.19M,16.78M) read by final idwt
    float* t0  = hp0 + (size_t)12582912;     // [16.78M,29.36M) level-0 attn pong
    float* ll1  = t0;                        //   +0     dead after idwt1
    float* hp1  = t0 + (size_t)1048576;      //   +1.05M dead after idwt1
    float* ta2  = t0 + (size_t)4194304;      //   +4.19M dead after idwt1
    float* lpta = t0 + (size_t)7340032;      //   +7.34M dead after lp pass-2
    float* tb  = out;                        // level-1 hp pong in d_out[0,3.15M)
    float* t1b = out;                        // level-0 ping in d_out[0,12.58M)
    unsigned short* wbuf = (unsigned short*)(out + (size_t)13631488); // 128 KB, clobbered only by final idwt

    prep_weights<<<256, 256, 0, stream>>>(
        P_lp[2], P_lp[4], P_lp[6], P_lp[8],
        P_hp[2], P_hp[4], P_hp[6], P_hp[8], wbuf);

    dwt_kernel<<<4 * 128 * 128 * 16 / 256, 256, 0, stream>>>(
        (const float4*)x, (float4*)ll0, (float4*)hp0, 4, 128, 128);
    dwt_kernel<<<4 * 64 * 64 * 16 / 256, 256, 0, stream>>>(
        (const float4*)ll0, (float4*)ll1, (float4*)hp1, 4, 64, 64);

    const unsigned short* lp_qkvT = wbuf;
    const unsigned short* lp_wpT  = wbuf + 24576;
    const unsigned short* hp_qkvT = wbuf + 32768;
    const unsigned short* hp_wpT  = wbuf + 32768 + 24576;

    auto mkjob = [](const float* xin, const float* mixsrc, const float* mixw,
                    float* xout, const float* basep, float rs,
                    const float* const* P, const unsigned short* qkvT,
                    const unsigned short* wpT) {
        Job jj;
        jj.xin = xin; jj.mixsrc = mixsrc; jj.mixw = mixw;
        jj.xout = xout; jj.basep = basep; jj.res_scale = rs;
        jj.ln_g = P[0]; jj.ln_b = P[1];
        jj.bq = P[3]; jj.bk = P[5]; jj.bv = P[7]; jj.bp = P[9];
        jj.wqkvT = qkvT; jj.wpT = wpT;
        return jj;
    };

    // ---- S=64 combined: lp (256 lines) + level-1 hp (768 lines) ----
    {
        Job a1 = mkjob(ll1, nullptr, nullptr, lpta, nullptr, 1.f, P_lp, lp_qkvT, lp_wpT);
        Job b1 = mkjob(nullptr, hp1, mw1, tb, nullptr, 1.f, P_hp, hp_qkvT, hp_wpT);
        axial_attn<64><<<1024, 512, 0, stream>>>(a1, b1, 256, 1);
        Job a2 = mkjob(lpta, nullptr, nullptr, ll1, ll1, 0.25f, P_lp, lp_qkvT, lp_wpT);
        Job b2 = mkjob(tb, nullptr, nullptr, ta2, nullptr, 1.f, P_hp, hp_qkvT, hp_wpT);
        axial_attn<64><<<1024, 512, 0, stream>>>(a2, b2, 256, 2);
    }
    idwt_kernel<<<4 * 64 * 64 * 16 / 256, 256, 0, stream>>>(
        (const float4*)ll1, (const float4*)hp1, (const float4*)ta2, 0.25f,
        (float4*)ll0, 4, 64, 64);

    // ---- S=128 level-0 hp (1536 lines) ----
    {
        Job c1 = mkjob(nullptr, hp0, mw0, t1b, nullptr, 1.f, P_hp, hp_qkvT, hp_wpT);
        axial_attn<128><<<1536, 512, 0, stream>>>(c1, c1, 1536, 1);
        Job c2 = mkjob(t1b, nullptr, nullptr, t0, nullptr, 1.f, P_hp, hp_qkvT, hp_wpT);
        axial_attn<128><<<1536, 512, 0, stream>>>(c2, c2, 1536, 2);
    }
    idwt_kernel<<<4 * 128 * 128 * 16 / 256, 256, 0, stream>>>(
        (const float4*)ll0, (const float4*)hp0, (const float4*)t0, 0.15f,
        (float4*)out, 4, 128, 128);
}

// Round 2
// 394.045 us; speedup vs baseline: 1.1491x; 1.1491x over previous
//
#include <hip/hip_runtime.h>

#define LN_EPS 1e-5f
#define QSCALE 0.25500526578425445f  // (1/sqrt(32)) * log2(e)

typedef __attribute__((ext_vector_type(8))) short bf16x8;
typedef __attribute__((ext_vector_type(4))) float f32x4;

#define MFMA16(A, B, C) __builtin_amdgcn_mfma_f32_16x16x32_bf16(A, B, C, 0, 0, 0)

// ---------- bf16 helpers ----------
static __device__ __forceinline__ unsigned short f2bf_rne(float f) {
    union { unsigned int i; float f; } c; c.f = f;
    unsigned int i = c.i;
    return (unsigned short)((i + 0x7fffu + ((i >> 16) & 1u)) >> 16);
}
static __device__ __forceinline__ void bfstore2(unsigned short* p, float x, float y) {
    *(unsigned int*)p = (unsigned int)f2bf_rne(x) | ((unsigned int)f2bf_rne(y) << 16);
}
static __device__ __forceinline__ unsigned pk2(float a, float b) {
    return __builtin_amdgcn_perm(__builtin_bit_cast(unsigned, b),
                                 __builtin_bit_cast(unsigned, a), 0x07060302u);
}
static __device__ __forceinline__ unsigned short tb16(float f) {
    return (unsigned short)(__builtin_bit_cast(unsigned, f) >> 16);
}
static __device__ __forceinline__ float bftrunc(float f) {
    return __builtin_bit_cast(float, __builtin_bit_cast(unsigned, f) & 0xFFFF0000u);
}

// ---------- DWT ----------
__global__ void dwt_kernel(const float4* __restrict__ in, float4* __restrict__ ll,
                           float4* __restrict__ hp, int B, int H2, int W2) {
    const int i = blockIdx.x * blockDim.x + threadIdx.x;
    const int total = B * H2 * W2 * 16;
    if (i >= total) return;
    const int c4 = i & 15;
    int t = i >> 4;
    const int w2 = t % W2; t /= W2;
    const int h2 = t % H2;
    const int b = t / H2;
    const int W = W2 * 2;
    const size_t base = (((size_t)b * (H2 * 2) + 2 * h2) * W + 2 * w2) * 16 + c4;
    const float4 x00 = in[base];
    const float4 x01 = in[base + 16];
    const float4 x10 = in[base + (size_t)W * 16];
    const float4 x11 = in[base + (size_t)W * 16 + 16];
    float4 vll, vlh, vhl, vhh;
#define DWTC(a) \
    vll.a = (x00.a + x01.a + x10.a + x11.a) * 0.5f; \
    vlh.a = (x00.a - x01.a + x10.a - x11.a) * 0.5f; \
    vhl.a = (x00.a + x01.a - x10.a - x11.a) * 0.5f; \
    vhh.a = (x00.a - x01.a - x10.a + x11.a) * 0.5f;
    DWTC(x) DWTC(y) DWTC(z) DWTC(w)
#undef DWTC
    const size_t oi = ((size_t)b * H2 + h2) * W2 + w2;
    ll[oi * 16 + c4] = vll;
    hp[oi * 48 + c4] = vlh;
    hp[oi * 48 + 16 + c4] = vhl;
    hp[oi * 48 + 32 + c4] = vhh;
}

// ---------- IDWT with fused hp_out = hp + gain*att ----------
__global__ void idwt_kernel(const float4* __restrict__ cur, const float4* __restrict__ hp,
                            const float4* __restrict__ att, float gain,
                            float4* __restrict__ out, int B, int H2, int W2) {
    const int i = blockIdx.x * blockDim.x + threadIdx.x;
    const int total = B * H2 * W2 * 16;
    if (i >= total) return;
    const int c4 = i & 15;
    int t = i >> 4;
    const int w2 = t % W2; t /= W2;
    const int h2 = t % H2;
    const int b = t / H2;
    const size_t oi = ((size_t)b * H2 + h2) * W2 + w2;
    const size_t sp = (size_t)h2 * W2 + w2;
    const size_t gstr = (size_t)B * H2 * W2;
    const float4 vll = cur[oi * 16 + c4];
    float4 vlh = hp[oi * 48 + c4];
    float4 vhl = hp[oi * 48 + 16 + c4];
    float4 vhh = hp[oi * 48 + 32 + c4];
    const float4 a0 = att[((size_t)b * H2 * W2 + sp) * 16 + c4];
    const float4 a1 = att[((size_t)b * H2 * W2 + gstr + sp) * 16 + c4];
    const float4 a2 = att[((size_t)b * H2 * W2 + 2 * gstr + sp) * 16 + c4];
#define ADDG(a) \
    vlh.a = fmaf(gain, a0.a, vlh.a); \
    vhl.a = fmaf(gain, a1.a, vhl.a); \
    vhh.a = fmaf(gain, a2.a, vhh.a);
    ADDG(x) ADDG(y) ADDG(z) ADDG(w)
#undef ADDG
    float4 x00, x01, x10, x11;
#define IDWTC(a) \
    x00.a = (vll.a + vlh.a + vhl.a + vhh.a) * 0.5f; \
    x01.a = (vll.a - vlh.a + vhl.a - vhh.a) * 0.5f; \
    x10.a = (vll.a + vlh.a - vhl.a - vhh.a) * 0.5f; \
    x11.a = (vll.a - vlh.a - vhl.a + vhh.a) * 0.5f;
    IDWTC(x) IDWTC(y) IDWTC(z) IDWTC(w)
#undef IDWTC
    const int W = W2 * 2;
    const size_t r0 = (((size_t)b * (H2 * 2) + 2 * h2) * W + 2 * w2) * 16 + c4;
    out[r0] = x00;
    out[r0 + 16] = x01;
    out[r0 + (size_t)W * 16] = x10;
    out[r0 + (size_t)W * 16 + 16] = x11;
}

// ---------- weight prep: f32 -> bf16 transposed; Wq scaled by QSCALE ----------
__global__ void prep_weights(const float* __restrict__ lwq, const float* __restrict__ lwk,
                             const float* __restrict__ lwv, const float* __restrict__ lwp,
                             const float* __restrict__ hwq, const float* __restrict__ hwk,
                             const float* __restrict__ hwv, const float* __restrict__ hwp,
                             unsigned short* __restrict__ wbuf) {
    const int i = blockIdx.x * blockDim.x + threadIdx.x;
    if (i >= 65536) return;
    const int set = i >> 15;
    const int r = i & 32767;
    const float* wq = set ? hwq : lwq;
    const float* wk = set ? hwk : lwk;
    const float* wv = set ? hwv : lwv;
    const float* wp = set ? hwp : lwp;
    float v;
    if (r < 24576) {
        const int nn = r >> 6, c = r & 63;
        const float* w = (nn < 128) ? wq : (nn < 256) ? wk : wv;
        v = w[c * 128 + (nn & 127)];
        if (nn < 128) v *= QSCALE;   // fold softmax scale*log2e into Wq
    } else {
        const int r2 = r - 24576;
        const int nn = r2 >> 7, d = r2 & 127;
        v = wp[d * 64 + nn];
    }
    wbuf[i] = f2bf_rne(v);
}

// ---------- job descriptor for the fused attention kernel ----------
struct Job {
    const float* xin;     // plain input (used when mixsrc == nullptr)
    const float* mixsrc;  // hp tensor (B,S,S,192); if set, phase A mixes groups
    const float* mixw;    // 3x3 mix matrix
    float* xout;
    const float* basep;   // residual base (nullptr = none)
    float res_scale;
    const float* ln_g; const float* ln_b;
    const float* bq; const float* bk; const float* bv; const float* bp;
    const unsigned short* wqkvT;  // bf16 [384][64], Wq pre-scaled
    const unsigned short* wpT;    // bf16 [64][128]
};

// ---------- fused axial attention: chunked K/V, double-buffered in dead Q ----------
// Q is hoisted to regs after phase B -> its LDS becomes the Kc/Vc double-buffer
// arena. K/V weights hoisted once per wave (wave w owns col-tile w). Row-sum of
// P done in VALU on bf16-truncated exps (matches MFMA(P,ones) numerics).
// LDS: S=128 -> 63,488 B, S=64 -> 55,296 B: 2 blocks/CU (16 waves).
template<int S>
__global__ __launch_bounds__(512, 4)
void axial_attn(Job jA, Job jB, int nA, int axis)
{
    constexpr int BS = 512;
    constexpr int NW = 8;               // waves
    constexpr int CK = 32;              // k-chunk rows
    constexpr int NCH = S / CK;         // chunks
    constexpr int NSI = S / 32;         // q-tiles per wave (2 waves/head)
    constexpr int CSTR = 40;            // Vc / Pb stride (shorts)

    __shared__ __align__(16) unsigned short Xs[S * 64];      // X after LN (swizzled)
    __shared__ __align__(16) unsigned short Arena[18432];    // Q/Y (S*128) | Kc x2 + Vc x2
    __shared__ __align__(16) unsigned short Pb[NW * 16 * CSTR];

    const int tid = threadIdx.x;
    const int lane = tid & 63;
    const int w = tid >> 6;
    const int n16 = lane & 15;
    const int quad = lane >> 4;

    const bool isB = (int)blockIdx.x >= nA;
    const Job j = isB ? jB : jA;
    const int line = isB ? (int)blockIdx.x - nA : (int)blockIdx.x;
    const int lb = line / S;
    const int lr = line - lb * S;
    size_t lbase, tstr; // float units
    if (axis == 1) { lbase = ((size_t)lb * S * S + lr) * 64; tstr = (size_t)S * 64; }
    else           { lbase = ((size_t)lb * S + lr) * (size_t)S * 64; tstr = 64; }

    // ---- persistent K/V weight fragments + biases (wave w owns col-tile w) ----
    const bf16x8 Wk0 = *(const bf16x8*)&j.wqkvT[((8 + w) * 16 + n16) * 64 + quad * 8];
    const bf16x8 Wk1 = *(const bf16x8*)&j.wqkvT[((8 + w) * 16 + n16) * 64 + 32 + quad * 8];
    const bf16x8 Wv0 = *(const bf16x8*)&j.wqkvT[((16 + w) * 16 + n16) * 64 + quad * 8];
    const bf16x8 Wv1 = *(const bf16x8*)&j.wqkvT[((16 + w) * 16 + n16) * 64 + 32 + quad * 8];
    const float bk = j.bk[w * 16 + n16];
    const float bv = j.bv[w * 16 + n16];

    // ---- Phase A: (optional group-mix) + LayerNorm -> Xs (bf16, swizzled) ----
    {
        const int sub = tid & 15;
        const float4 g4 = ((const float4*)j.ln_g)[sub];
        const float4 be4 = ((const float4*)j.ln_b)[sub];
        const float4* x4 = (const float4*)j.xin;
        const float4* hp4 = (const float4*)j.mixsrc;
        const size_t lbase4 = lbase >> 2, tstr4 = tstr >> 2;
        float m0, m1, m2; int bimg;
        if (hp4) {
            const int g = lb >> 2;      // B = 4 images
            bimg = lb & 3;
            m0 = j.mixw[g * 3 + 0]; m1 = j.mixw[g * 3 + 1]; m2 = j.mixw[g * 3 + 2];
        }
        for (int t = (tid >> 4); t < S; t += BS / 16) {
            float4 v;
            if (hp4) {
                const int pos = (axis == 1) ? (t * S + lr) : (lr * S + t);
                const size_t hb = ((size_t)bimg * S * S + pos) * 48 + sub;
                const float4 h0 = hp4[hb];
                const float4 h1 = hp4[hb + 16];
                const float4 h2 = hp4[hb + 32];
                v.x = m0 * h0.x + m1 * h1.x + m2 * h2.x;
                v.y = m0 * h0.y + m1 * h1.y + m2 * h2.y;
                v.z = m0 * h0.z + m1 * h1.z + m2 * h2.z;
                v.w = m0 * h0.w + m1 * h1.w + m2 * h2.w;
            } else {
                v = x4[lbase4 + (size_t)t * tstr4 + sub];
            }
            float s = v.x + v.y + v.z + v.w;
            float ss = v.x * v.x + v.y * v.y + v.z * v.z + v.w * v.w;
            #pragma unroll
            for (int m = 1; m < 16; m <<= 1) {
                s += __shfl_xor(s, m);
                ss += __shfl_xor(ss, m);
            }
            const float mean = s * 0.015625f;
            const float rstd = rsqrtf(ss * 0.015625f - mean * mean + LN_EPS);
            unsigned short* xr = &Xs[(t << 6) + ((sub * 4) ^ ((t & 7) << 3))];
            bfstore2(xr,     (v.x - mean) * rstd * g4.x + be4.x,
                             (v.y - mean) * rstd * g4.y + be4.y);
            bfstore2(xr + 2, (v.z - mean) * rstd * g4.z + be4.z,
                             (v.w - mean) * rstd * g4.w + be4.w);
        }
    }
    __syncthreads();

    // ---- Phase B: Q = X @ Wq + bq into Arena (swizzled stride-128) ----
    {
        const float bias = j.bq[w * 16 + n16] * QSCALE;
        const bf16x8 Bq0 = *(const bf16x8*)&j.wqkvT[(w * 16 + n16) * 64 + quad * 8];
        const bf16x8 Bq1 = *(const bf16x8*)&j.wqkvT[(w * 16 + n16) * 64 + 32 + quad * 8];
        #pragma unroll
        for (int mt = 0; mt < S / 16; ++mt) {
            const int xr = mt * 16 + n16;
            const int xm = (xr & 7) << 3;
            const bf16x8 A0 = *(const bf16x8*)&Xs[(xr << 6) + ((quad * 8) ^ xm)];
            const bf16x8 A1 = *(const bf16x8*)&Xs[(xr << 6) + ((32 + quad * 8) ^ xm)];
            f32x4 acc = {bias, bias, bias, bias};
            acc = MFMA16(A0, Bq0, acc);
            acc = MFMA16(A1, Bq1, acc);
            const int row0 = mt * 16 + quad * 4;
            #pragma unroll
            for (int r = 0; r < 4; ++r) {
                const int rr = row0 + r;
                Arena[(rr << 7) + ((w * 16 + n16) ^ ((rr & 7) << 3))] = tb16(acc[r]);
            }
        }
    }
    __syncthreads();

    // ---- hoist Q fragments; Arena becomes Kc/Vc double-buffer ----
    const int h = w >> 1;
    const int sub = w & 1;
    const int hoff = h * 32;
    unsigned short* pbw = &Pb[w * 16 * CSTR];

    bf16x8 qb[NSI];
    #pragma unroll
    for (int si = 0; si < NSI; ++si) {
        const int qr = (sub * NSI + si) * 16 + n16;
        qb[si] = *(const bf16x8*)&Arena[(qr << 7) + ((hoff + quad * 8) ^ ((qr & 7) << 3))];
    }
    f32x4 y0[NSI], y1[NSI];
    float rsum[NSI];
    #pragma unroll
    for (int si = 0; si < NSI; ++si) {
        y0[si] = (f32x4){0.f, 0.f, 0.f, 0.f};
        y1[si] = (f32x4){0.f, 0.f, 0.f, 0.f};
        rsum[si] = 0.f;
    }
    __syncthreads();   // all qb hoisted before Arena is overwritten

    // ---- chunk loop: produce(kc+1) overlaps consume(kc); 1 barrier/chunk ----
    auto produce = [&](int kc, int buf) {
        const int k0 = kc * CK;
        unsigned short* Kc = &Arena[buf * 4096];
        unsigned short* Vc = &Arena[8192 + buf * 5120];
        #pragma unroll
        for (int mtl = 0; mtl < 2; ++mtl) {
            const int xr = k0 + mtl * 16 + n16;
            const int xm = (xr & 7) << 3;
            const bf16x8 A0 = *(const bf16x8*)&Xs[(xr << 6) + ((quad * 8) ^ xm)];
            const bf16x8 A1 = *(const bf16x8*)&Xs[(xr << 6) + ((32 + quad * 8) ^ xm)];
            f32x4 ak = {bk, bk, bk, bk};
            ak = MFMA16(A0, Wk0, ak);
            ak = MFMA16(A1, Wk1, ak);
            const int row0 = mtl * 16 + quad * 4;
            #pragma unroll
            for (int r = 0; r < 4; ++r) {
                const int rr = row0 + r;
                Kc[(rr << 7) + ((w * 16 + n16) ^ ((rr & 7) << 3))] = tb16(ak[r]);
            }
            f32x4 av = {bv, bv, bv, bv};
            av = MFMA16(A0, Wv0, av);
            av = MFMA16(A1, Wv1, av);
            *(uint2*)&Vc[(w * 16 + n16) * CSTR + mtl * 16 + quad * 4] =
                make_uint2(pk2(av[0], av[1]), pk2(av[2], av[3]));
        }
    };
    auto consume = [&](int buf) {
        const unsigned short* Kc = &Arena[buf * 4096];
        const unsigned short* Vc = &Arena[8192 + buf * 5120];
        const int km = (n16 & 7) << 3;
        const bf16x8 ka0 = *(const bf16x8*)&Kc[(n16 << 7) + ((hoff + quad * 8) ^ km)];
        const bf16x8 ka1 = *(const bf16x8*)&Kc[((16 + n16) << 7) + ((hoff + quad * 8) ^ km)];
        const bf16x8 vb0 = *(const bf16x8*)&Vc[(hoff + n16) * CSTR + quad * 8];
        const bf16x8 vb1 = *(const bf16x8*)&Vc[(hoff + 16 + n16) * CSTR + quad * 8];
        #pragma unroll
        for (int si = 0; si < NSI; ++si) {
            f32x4 sc0 = {0.f, 0.f, 0.f, 0.f};
            f32x4 sc1 = {0.f, 0.f, 0.f, 0.f};
            sc0 = MFMA16(ka0, qb[si], sc0);
            sc1 = MFMA16(ka1, qb[si], sc1);
            const float e0 = __builtin_amdgcn_exp2f(sc0[0]);
            const float e1 = __builtin_amdgcn_exp2f(sc0[1]);
            const float e2 = __builtin_amdgcn_exp2f(sc0[2]);
            const float e3 = __builtin_amdgcn_exp2f(sc0[3]);
            const float e4 = __builtin_amdgcn_exp2f(sc1[0]);
            const float e5 = __builtin_amdgcn_exp2f(sc1[1]);
            const float e6 = __builtin_amdgcn_exp2f(sc1[2]);
            const float e7 = __builtin_amdgcn_exp2f(sc1[3]);
            // denominator on bf16-truncated values (matches stored P exactly)
            rsum[si] += ((bftrunc(e0) + bftrunc(e1)) + (bftrunc(e2) + bftrunc(e3)))
                      + ((bftrunc(e4) + bftrunc(e5)) + (bftrunc(e6) + bftrunc(e7)));
            *(uint2*)&pbw[n16 * CSTR + quad * 4] =
                make_uint2(pk2(e0, e1), pk2(e2, e3));
            *(uint2*)&pbw[n16 * CSTR + 16 + quad * 4] =
                make_uint2(pk2(e4, e5), pk2(e6, e7));
            const bf16x8 pa = *(const bf16x8*)&pbw[n16 * CSTR + quad * 8];
            y0[si] = MFMA16(pa, vb0, y0[si]);
            y1[si] = MFMA16(pa, vb1, y1[si]);
        }
    };

    produce(0, 0);
    __syncthreads();
    for (int kc = 0; kc < NCH; ++kc) {
        if (kc + 1 < NCH) produce(kc + 1, (kc + 1) & 1);
        consume(kc & 1);
        __syncthreads();
    }

    // ---- Y normalize -> Arena (Kc/Vc dead) ----
    #pragma unroll
    for (int si = 0; si < NSI; ++si) {
        float red = rsum[si];
        red += __shfl_xor(red, 16);
        red += __shfl_xor(red, 32);
        const int q0 = (sub * NSI + si) * 16;
        #pragma unroll
        for (int r = 0; r < 4; ++r) {
            const float inv = __builtin_amdgcn_rcpf(__shfl(red, quad * 4 + r));
            const int row = q0 + quad * 4 + r;
            const int m = (row & 7) << 3;
            Arena[(row << 7) + ((hoff + n16) ^ m)]      = tb16(y0[si][r] * inv);
            Arena[(row << 7) + ((hoff + 16 + n16) ^ m)] = tb16(y1[si][r] * inv);
        }
    }
    __syncthreads();

    // ---- Phase D: out = Y @ Wp + bp (+ residual) ----
    {
        constexpr int TD = (S / 16) * 4 / NW;   // 4 for S=128, 2 for S=64
        const int mt = (w * TD) >> 2;           // constant per wave
        const int nt0 = (w * TD) & 3;
        const int m0 = mt * 16;
        const int ym = (n16 & 7) << 3;
        bf16x8 pa[4];
        #pragma unroll
        for (int kt = 0; kt < 4; ++kt)
            pa[kt] = *(const bf16x8*)&Arena[((m0 + n16) << 7) + ((kt * 32 + quad * 8) ^ ym)];
        #pragma unroll
        for (int i = 0; i < TD; ++i) {
            const int nt = nt0 + i;
            const float bias = j.bp[nt * 16 + n16];
            f32x4 acc = {bias, bias, bias, bias};
            #pragma unroll
            for (int kt = 0; kt < 4; ++kt) {
                const bf16x8 wb = *(const bf16x8*)&j.wpT[(nt * 16 + n16) * 128 + kt * 32 + quad * 8];
                acc = MFMA16(pa[kt], wb, acc);
            }
            #pragma unroll
            for (int r = 0; r < 4; ++r) {
                const size_t gi = lbase + (size_t)(m0 + quad * 4 + r) * tstr + nt * 16 + n16;
                float v = acc[r];
                if (j.basep) v = fmaf(j.res_scale, v, j.basep[gi]);
                j.xout[gi] = v;
            }
        }
    }
}

extern "C" void kernel_launch(void* const* d_in, const int* in_sizes, int n_in,
                              void* d_out, int out_size, void* d_ws, size_t ws_size,
                              hipStream_t stream) {
    (void)in_sizes; (void)n_in; (void)out_size; (void)ws_size;
    const float* x = (const float*)d_in[0];
    const float* P_lp[10];
    const float* P_hp[10];
    for (int i = 0; i < 10; ++i) P_lp[i] = (const float*)d_in[1 + i];
    for (int i = 0; i < 10; ++i) P_hp[i] = (const float*)d_in[11 + i];
    const float* mw0 = (const float*)d_in[21];
    const float* mw1 = (const float*)d_in[22];
    float* out = (float*)d_out;
    float* ws = (float*)d_ws;

    // ---- workspace map (floats) ----
    float* ll0 = ws;                         // [0,4.19M)     cur0; read by final idwt
    float* hp0 = ll0 + (size_t)4194304;      // [4.19M,16.78M) read by final idwt
    float* t0  = hp0 + (size_t)12582912;     // [16.78M,29.36M) level-0 attn pong
    float* ll1  = t0;                        //   +0     dead after idwt1
    float* hp1  = t0 + (size_t)1048576;      //   +1.05M dead after idwt1
    float* ta2  = t0 + (size_t)4194304;      //   +4.19M dead after idwt1
    float* lpta = t0 + (size_t)7340032;      //   +7.34M dead after lp pass-2
    float* tb  = out;                        // level-1 hp pong in d_out[0,3.15M)
    float* t1b = out;                        // level-0 ping in d_out[0,12.58M)
    unsigned short* wbuf = (unsigned short*)(out + (size_t)13631488); // 128 KB, clobbered only by final idwt

    prep_weights<<<256, 256, 0, stream>>>(
        P_lp[2], P_lp[4], P_lp[6], P_lp[8],
        P_hp[2], P_hp[4], P_hp[6], P_hp[8], wbuf);

    dwt_kernel<<<4 * 128 * 128 * 16 / 256, 256, 0, stream>>>(
        (const float4*)x, (float4*)ll0, (float4*)hp0, 4, 128, 128);
    dwt_kernel<<<4 * 64 * 64 * 16 / 256, 256, 0, stream>>>(
        (const float4*)ll0, (float4*)ll1, (float4*)hp1, 4, 64, 64);

    const unsigned short* lp_qkvT = wbuf;
    const unsigned short* lp_wpT  = wbuf + 24576;
    const unsigned short* hp_qkvT = wbuf + 32768;
    const unsigned short* hp_wpT  = wbuf + 32768 + 24576;

    auto mkjob = [](const float* xin, const float* mixsrc, const float* mixw,
                    float* xout, const float* basep, float rs,
                    const float* const* P, const unsigned short* qkvT,
                    const unsigned short* wpT) {
        Job jj;
        jj.xin = xin; jj.mixsrc = mixsrc; jj.mixw = mixw;
        jj.xout = xout; jj.basep = basep; jj.res_scale = rs;
        jj.ln_g = P[0]; jj.ln_b = P[1];
        jj.bq = P[3]; jj.bk = P[5]; jj.bv = P[7]; jj.bp = P[9];
        jj.wqkvT = qkvT; jj.wpT = wpT;
        return jj;
    };

    // ---- S=64 combined: lp (256 lines) + level-1 hp (768 lines) ----
    {
        Job a1 = mkjob(ll1, nullptr, nullptr, lpta, nullptr, 1.f, P_lp, lp_qkvT, lp_wpT);
        Job b1 = mkjob(nullptr, hp1, mw1, tb, nullptr, 1.f, P_hp, hp_qkvT, hp_wpT);
        axial_attn<64><<<1024, 512, 0, stream>>>(a1, b1, 256, 1);
        Job a2 = mkjob(lpta, nullptr, nullptr, ll1, ll1, 0.25f, P_lp, lp_qkvT, lp_wpT);
        Job b2 = mkjob(tb, nullptr, nullptr, ta2, nullptr, 1.f, P_hp, hp_qkvT, hp_wpT);
        axial_attn<64><<<1024, 512, 0, stream>>>(a2, b2, 256, 2);
    }
    idwt_kernel<<<4 * 64 * 64 * 16 / 256, 256, 0, stream>>>(
        (const float4*)ll1, (const float4*)hp1, (const float4*)ta2, 0.25f,
        (float4*)ll0, 4, 64, 64);

    // ---- S=128 level-0 hp (1536 lines) ----
    {
        Job c1 = mkjob(nullptr, hp0, mw0, t1b, nullptr, 1.f, P_hp, hp_qkvT, hp_wpT);
        axial_attn<128><<<1536, 512, 0, stream>>>(c1, c1, 1536, 1);
        Job c2 = mkjob(t1b, nullptr, nullptr, t0, nullptr, 1.f, P_hp, hp_qkvT, hp_wpT);
        axial_attn<128><<<1536, 512, 0, stream>>>(c2, c2, 1536, 2);
    }
    idwt_kernel<<<4 * 128 * 128 * 16 / 256, 256, 0, stream>>>(
        (const float4*)ll0, (const float4*)hp0, (const float4*)t0, 0.15f,
        (float4*)out, 4, 128, 128);
}